// Round 5
// baseline (448.501 us; speedup 1.0000x reference)
//
#include <hip/hip_runtime.h>
#include <cstddef>

// Vanilla tanh-RNN: B=4096, T=2048, I=4, H=20, then Linear(20->4) on h_last.
//
// Round-10: offload 9 broadcasts from the VALU to the DS pipe (ds_bpermute).
//
// Law (R6-R9b, 4 kernels): wall = ~6.1 cyc x VALU-inst count, invariant
// under class mix, schedule (3 null experiments), and wave count (R5).
// Whatever per-SIMD resource this is, it's consumed per VALU instruction.
// Only lever: fewer VALU instructions. The DS pipe is nearly idle
// (1 ds_read/step) -> move broadcast work there.
//
// Change vs R9b (chain membership identical, values bit-identical):
//  * 4 quad broadcasts + rotations r=12..15 + the r=0 identity copy are
//    now ds_bpermute_b32 (LGKM pipe), issued at the TOP of the MAC block
//    (they depend only on the fresh h), results in fixed regs v42-v58.
//  * Their 9 consuming pk_fmas move to the tail behind one
//    s_waitcnt lgkmcnt(0) — ~25 VALU insts (~150 cyc) of latency cover.
//  * Quads share ONE index reg via offset:0/4/8/12 (addr = 4*(lane&~3)+4c).
//  * VALU/step: 55 -> 46. DS/step: 1 -> 10 (4 waves/CU x 10 x ~5 cyc
//    ~ 200 cyc on DS pipe, hidden under ~283 cyc of VALU).
//
// Fixed-reg passing (v42-v65): clobbered in BOTH asm blocks; every value
// live across the tail block (weights, queue, xa/xb) is forced out of
// v42-v65 by the tail's clobber list, so nothing the compiler schedules
// between the blocks can land in them.
//
// Layout identical to R4-R9b: 16 lanes/element, 4 elem/wave, 1024 waves =
// 1 wave/SIMD. Lane j holds h_j (hA) and h_{16+(j&3)} (hB, quad-repl).
// row_ror:r / bperm deliver h_{(j-r)&15}; weights pre-permuted, pre-scaled
// by 2*log2(e) so tanh = 1 - 2*rcp(exp2(s)+1). Cross-step state rA,rB
// (post-rcp values); h finished at the top of the next MAC (R9b pattern).
//
// x staging: R3-R9b wave-local LDS double buffer, zero barriers.

typedef float f32x2 __attribute__((ext_vector_type(2)));
typedef float f32x4 __attribute__((ext_vector_type(4)));

constexpr int Tn   = 2048;
constexpr int Hn   = 20;
constexpr int EPB  = 16;   // elements per 256-thread block
constexpr int SB   = 16;   // steps per staging block
constexpr int NBLK = Tn / SB;

__global__ __launch_bounds__(256, 1) void rnn_fwd(
    const float* __restrict__ x,     // [B, T, 4]
    const float* __restrict__ h0,    // [B, 20]
    const float* __restrict__ W_ih,  // [20, 4]
    const float* __restrict__ W_hh,  // [20, 20]
    const float* __restrict__ b_ih,  // [20]
    const float* __restrict__ b_hh,  // [20]
    const float* __restrict__ fc_w,  // [4, 20]
    const float* __restrict__ fc_b,  // [4]
    float* __restrict__ out)         // [B, 4]
{
    __shared__ __align__(16) f32x4 xlds[2][EPB][SB + 1];
    __shared__ float hsh[EPB][24];

    const int tid  = threadIdx.x;
    const int j    = tid & 15;            // lane within row = A-target unit
    const int e    = tid >> 4;            // element slot in block (0..15)
    const int b    = blockIdx.x * EPB + e;
    const int uB   = 16 + (j & 3);        // B-target unit
    const int lane = tid & 63;            // lane within wave

    // bpermute byte-indices (wave-relative lane * 4)
    const int iQ  = (lane & ~3) << 2;                          // quad base (+offset:4c)
    const int iID = lane << 2;                                 // identity (r=0)
    const int i12 = (((lane & ~15) | ((lane - 12) & 15))) << 2;
    const int i13 = (((lane & ~15) | ((lane - 13) & 15))) << 2;
    const int i14 = (((lane & ~15) | ((lane - 14) & 15))) << 2;
    const int i15 = (((lane & ~15) | ((lane - 15) & 15))) << 2;

    const float S = 2.88539008177792681472f;  // 2/ln(2)

    // Pair weights: lo = A-chain (unit j), hi = B-chain (unit uB).
    f32x2 w2[16];
#pragma unroll
    for (int r = 0; r < 16; ++r) {
        const int k = (j - r) & 15;       // unit delivered by rotation r
        w2[r] = f32x2{S * W_hh[j * Hn + k], S * W_hh[uB * Hn + k]};
    }
    f32x2 wq2[4], xiw[4];
#pragma unroll
    for (int c = 0; c < 4; ++c) {
        wq2[c] = f32x2{S * W_hh[j * Hn + 16 + c], S * W_hh[uB * Hn + 16 + c]};
        xiw[c] = f32x2{S * W_ih[j * 4 + c],       S * W_ih[uB * 4 + c]};
    }
    f32x2 bias2 = f32x2{S * (b_ih[j] + b_hh[j]), S * (b_ih[uB] + b_hh[uB])};

    // ---- initial state: seed r so that h = -2*r + 1 reproduces h0 ----
    float rA = 0.5f * (1.0f - h0[b * Hn + j]);
    float rB = 0.5f * (1.0f - h0[b * Hn + uB]);
    float hA, hB;                         // produced by each MAC block

    const f32x4* __restrict__ xp =
        reinterpret_cast<const f32x4*>(x) + (size_t)b * Tn;

#define DPPM " row_mask:0xf bank_mask:0xf\n\t"
#define PKB  " op_sel:[0,0,0] op_sel_hi:[1,0,1]\n\t"   /* bcast src1 word0 */
#define CLB  "v42","v43","v44","v45","v46","v47","v48","v49","v50","v51",     \
             "v52","v53","v54","v55","v56","v57","v58","v59","v60","v61",     \
             "v62","v63","v64","v65"

    // MAC block: finish tanh, issue 9 bperms (DS pipe), 11 DPP rotations.
#define STEP_MAC() do {                                                       \
    asm volatile(                                                             \
  "v_fma_f32 %[hB], %[rB], -2.0, 1.0\n\t"                                     \
  "v_fma_f32 %[hA], %[rA], -2.0, 1.0\n\t"                                     \
  "ds_bpermute_b32 v42, %[iQ], %[hB]\n\t"                                     \
  "ds_bpermute_b32 v44, %[iQ], %[hB] offset:4\n\t"                            \
  "ds_bpermute_b32 v46, %[iQ], %[hB] offset:8\n\t"                            \
  "ds_bpermute_b32 v48, %[iQ], %[hB] offset:12\n\t"                           \
  "ds_bpermute_b32 v50, %[i12], %[hA]\n\t"                                    \
  "ds_bpermute_b32 v52, %[i13], %[hA]\n\t"                                    \
  "ds_bpermute_b32 v54, %[i14], %[hA]\n\t"                                    \
  "ds_bpermute_b32 v56, %[i15], %[hA]\n\t"                                    \
  "ds_bpermute_b32 v58, %[iID], %[hA]\n\t"                                    \
  "v_mov_b32_dpp v60, %[hA] row_ror:1"  DPPM                                  \
  "v_mov_b32_dpp v62, %[hA] row_ror:2"  DPPM                                  \
  "v_pk_fma_f32 %[Q], %[w1], v[60:61], %[Q]" PKB                              \
  "v_mov_b32_dpp v64, %[hA] row_ror:3"  DPPM                                  \
  "v_pk_fma_f32 %[R], %[w2], v[62:63], %[R]" PKB                              \
  "v_mov_b32_dpp v60, %[hA] row_ror:4"  DPPM                                  \
  "v_pk_fma_f32 %[Sc], %[w3], v[64:65], %[Sc]" PKB                            \
  "v_mov_b32_dpp v62, %[hA] row_ror:5"  DPPM                                  \
  "v_pk_fma_f32 %[P], %[w4], v[60:61], %[P]" PKB                              \
  "v_mov_b32_dpp v64, %[hA] row_ror:6"  DPPM                                  \
  "v_pk_fma_f32 %[Q], %[w5], v[62:63], %[Q]" PKB                              \
  "v_mov_b32_dpp v60, %[hA] row_ror:7"  DPPM                                  \
  "v_pk_fma_f32 %[R], %[w6], v[64:65], %[R]" PKB                              \
  "v_mov_b32_dpp v62, %[hA] row_ror:8"  DPPM                                  \
  "v_pk_fma_f32 %[Sc], %[w7], v[60:61], %[Sc]" PKB                            \
  "v_mov_b32_dpp v64, %[hA] row_ror:9"  DPPM                                  \
  "v_pk_fma_f32 %[P], %[w8], v[62:63], %[P]" PKB                              \
  "v_mov_b32_dpp v60, %[hA] row_ror:10" DPPM                                  \
  "v_pk_fma_f32 %[Q], %[w9], v[64:65], %[Q]" PKB                              \
  "v_mov_b32_dpp v62, %[hA] row_ror:11" DPPM                                  \
  "v_pk_fma_f32 %[R], %[w10], v[60:61], %[R]" PKB                             \
  "v_pk_fma_f32 %[Sc], %[w11], v[62:63], %[Sc]"                               \
  " op_sel:[0,0,0] op_sel_hi:[1,0,1]"                                         \
  : [hA] "=&v"(hA), [hB] "=&v"(hB),                                           \
    [P] "+v"(xiP), [Q] "+v"(xiQ), [R] "+v"(xiR), [Sc] "+v"(xiS)               \
  : [rA] "v"(rA), [rB] "v"(rB),                                               \
    [w1] "v"(w2[1]), [w2] "v"(w2[2]),  [w3] "v"(w2[3]),  [w4] "v"(w2[4]),     \
    [w5] "v"(w2[5]), [w6] "v"(w2[6]),  [w7] "v"(w2[7]),  [w8] "v"(w2[8]),     \
    [w9] "v"(w2[9]), [w10] "v"(w2[10]),[w11] "v"(w2[11]),                     \
    [iQ] "v"(iQ), [iID] "v"(iID),                                             \
    [i12] "v"(i12), [i13] "v"(i13), [i14] "v"(i14), [i15] "v"(i15)            \
  : CLB);                                                                     \
} while (0)

    // Tail: wait bperms, 9 pk_fma, combine + exp/rcp, xi(t+1) in the gaps.
#define STEP_TAIL(XV) do {                                                    \
    f32x2 xa_ = __builtin_shufflevector((XV), (XV), 0, 1);                    \
    f32x2 xb_ = __builtin_shufflevector((XV), (XV), 2, 3);                    \
    asm volatile(                                                             \
  "s_waitcnt lgkmcnt(0)\n\t"                                                  \
  "v_pk_fma_f32 %[P],  %[w0],  v[58:59], %[P]" PKB   /* r=0 identity */       \
  "v_pk_fma_f32 %[Q],  %[w13], v[52:53], %[Q]" PKB   /* r=13 */               \
  "v_pk_fma_f32 %[R],  %[w14], v[54:55], %[R]" PKB   /* r=14 */               \
  "v_pk_fma_f32 %[Sc], %[w15], v[56:57], %[Sc]" PKB  /* r=15 */               \
  "v_pk_fma_f32 %[P],  %[w12], v[50:51], %[P]" PKB   /* r=12 */               \
  "v_pk_fma_f32 %[Q],  %[q1w], v[44:45], %[Q]" PKB   /* quad 1 */             \
  "v_pk_fma_f32 %[R],  %[q2w], v[46:47], %[R]" PKB   /* quad 2 */             \
  "v_pk_fma_f32 %[Sc], %[q3w], v[48:49], %[Sc]" PKB  /* quad 3 */             \
  "v_pk_fma_f32 %[P],  %[q0w], v[42:43], %[P]" PKB   /* quad 0 */             \
  "v_pk_add_f32 v[60:61], %[P], %[Q]\n\t"                                     \
  "v_pk_fma_f32 %[P], %[x0], %[xa], %[b2]" PKB                                \
  "v_pk_add_f32 v[62:63], %[R], %[Sc]\n\t"                                    \
  "v_pk_mul_f32 %[Q], %[x1], %[xa] op_sel:[0,1] op_sel_hi:[1,1]\n\t"          \
  "v_pk_mul_f32 %[R], %[x2], %[xb] op_sel:[0,0] op_sel_hi:[1,0]\n\t"          \
  "v_pk_add_f32 v[60:61], v[60:61], v[62:63]\n\t"                             \
  "v_pk_mul_f32 %[Sc], %[x3], %[xb] op_sel:[0,1] op_sel_hi:[1,1]\n\t"         \
  "v_exp_f32 v64, v61\n\t"                                                    \
  "v_exp_f32 v65, v60\n\t"                                                    \
  "v_add_f32 v64, 1.0, v64\n\t"                                               \
  "v_add_f32 v65, 1.0, v65\n\t"                                               \
  "v_rcp_f32 %[rB], v64\n\t"                                                  \
  "v_rcp_f32 %[rA], v65"                                                      \
  : [rA] "=&v"(rA), [rB] "=&v"(rB),                                           \
    [P] "+v"(xiP), [Q] "+v"(xiQ), [R] "+v"(xiR), [Sc] "+v"(xiS)               \
  : [w0] "v"(w2[0]), [w12] "v"(w2[12]), [w13] "v"(w2[13]),                    \
    [w14] "v"(w2[14]), [w15] "v"(w2[15]),                                     \
    [q0w] "v"(wq2[0]), [q1w] "v"(wq2[1]), [q2w] "v"(wq2[2]), [q3w] "v"(wq2[3]),\
    [xa] "v"(xa_), [xb] "v"(xb_),                                             \
    [x0] "v"(xiw[0]), [x1] "v"(xiw[1]), [x2] "v"(xiw[2]), [x3] "v"(xiw[3]),   \
    [b2] "v"(bias2)                                                           \
  : CLB);                                                                     \
} while (0)

#define STEP(XV) do { STEP_MAC(); STEP_TAIL(XV); } while (0)

    // ---- prologue: stage block 0, compute xi(0), prime queue at x[1..3] ----
    xlds[0][e][j] = xp[j];                // lane j -> row j (coalesced)
    f32x4 x0v = xp[0];
    f32x2 xiP = f32x2{__builtin_fmaf(x0v[0], xiw[0][0], bias2[0]),
                      __builtin_fmaf(x0v[0], xiw[0][1], bias2[1])};
    f32x2 xiQ = f32x2{x0v[1] * xiw[1][0], x0v[1] * xiw[1][1]};
    f32x2 xiR = f32x2{x0v[2] * xiw[2][0], x0v[2] * xiw[2][1]};
    f32x2 xiS = f32x2{x0v[3] * xiw[3][0], x0v[3] * xiw[3][1]};
    f32x4 q0 = xlds[0][e][1];
    f32x4 q1 = xlds[0][e][2];
    f32x4 q2 = xlds[0][e][3];

    int cur = 0;
#pragma unroll 1
    for (int k = 0; k < NBLK; ++k) {
        const int kn = (k + 1 < NBLK) ? (k + 1) : (NBLK - 1);  // tail reload
        f32x4 xr = xp[kn * SB + j];       // global load at block TOP
        const int nxt = cur ^ 1;
#pragma unroll
        for (int s = 0; s < SB - 4; ++s) {                     // s = 0..11
            f32x4 xv = q0; q0 = q1; q1 = q2;
            q2 = xlds[cur][e][s + 4];     // 3-step LDS lookahead (shifted)
            STEP(xv);
        }
        xlds[nxt][e][j] = xr;             // prior reads of nxt already issued
        { f32x4 xv = q0; q0 = q1; q1 = q2; q2 = xlds[nxt][e][0]; STEP(xv); }
        { f32x4 xv = q0; q0 = q1; q1 = q2; q2 = xlds[nxt][e][1]; STEP(xv); }
        { f32x4 xv = q0; q0 = q1; q1 = q2; q2 = xlds[nxt][e][2]; STEP(xv); }
        { f32x4 xv = q0; q0 = q1; q1 = q2; q2 = xlds[nxt][e][3]; STEP(xv); }
        cur = nxt;
    }
#undef STEP
#undef STEP_MAC
#undef STEP_TAIL
#undef PKB
#undef DPPM
#undef CLB

    // ---- finish the last tanh: h(2048) = -2*r(2047) + 1 ----
    const float hAf = __builtin_fmaf(-2.0f, rA, 1.0f);
    const float hBf = __builtin_fmaf(-2.0f, rB, 1.0f);

    // ---- epilogue: out[b][m] = fc_b[m] + sum_k h[k] * fc_w[m][k] ----
    hsh[e][j] = hAf;                      // units 0..15
    if (j < 4) hsh[e][16 + j] = hBf;      // lane j holds unit 16+j
    if (j < 4) {
        float o = fc_b[j];
#pragma unroll
        for (int kk = 0; kk < Hn; ++kk)
            o = __builtin_fmaf(hsh[e][kk], fc_w[j * Hn + kk], o);
        out[b * 4 + j] = o;
    }
}

extern "C" void kernel_launch(void* const* d_in, const int* in_sizes, int n_in,
                              void* d_out, int out_size, void* d_ws, size_t ws_size,
                              hipStream_t stream) {
    const float* x    = (const float*)d_in[0];
    const float* h0   = (const float*)d_in[1];
    const float* W_ih = (const float*)d_in[2];
    const float* W_hh = (const float*)d_in[3];
    const float* b_ih = (const float*)d_in[4];
    const float* b_hh = (const float*)d_in[5];
    const float* fc_w = (const float*)d_in[6];
    const float* fc_b = (const float*)d_in[7];
    float* out = (float*)d_out;

    // 4096 elements / 16 per block = 256 blocks = 1024 waves = 1 wave/SIMD.
    rnn_fwd<<<dim3(256), dim3(256), 0, stream>>>(x, h0, W_ih, W_hh, b_ih, b_hh,
                                                 fc_w, fc_b, out);
}

// Round 6
// 424.996 us; speedup vs baseline: 1.0553x; 1.0553x over previous
//
#include <hip/hip_runtime.h>
#include <cstddef>

// Vanilla tanh-RNN: B=4096, T=2048, I=4, H=20, then Linear(20->4) on h_last.
//
// Round-11: rebalanced DS offload (K=4) + broadcast elimination + 2 chains.
//
// Quantitative model (R6-R10):
//   VALU: busy = 4.7 cyc/inst exactly (R9b 258/55, R10 216/46); wall adds
//         ~1.4/inst of unfillable overhead -> ~6.1 cyc/inst per SIMD.
//   DS:   ds_bpermute ~10 cyc/op on the per-CU DS pipe (R10: wall 405 =
//         4 waves x (9 bperm x 10 + ds_read 13) — DS-bound, VALUBusy 53%).
//   wall = max(6.1 x N_valu, 4 x (10 x N_bperm + 13)).
// R10 overshot (K=9). K=4: DS = 212 < VALU = 287. And cut VALU count:
//  * hA/hB written into FIXED EVEN PAIRS (v40, v44): the r=0 and quad-own
//    pk_fmas read v[40:41]/v[44:45] directly via op_sel_hi[1]=0 word0
//    broadcast — no mov at all for those two terms.
//  * quad terms c=1..3 via quad_perm ROTATIONS [1,2,3,0]/[2,3,0,1]/
//    [3,0,1,2] with lane-permuted weights (3 movs, was 4 broadcasts).
//  * r=12..15 via ds_bpermute (DS pipe), consumed in tail after
//    s_waitcnt lgkmcnt(0).
//  * 2 accumulator chains (P,Q) — R5-R9b: dependency spacing is
//    irrelevant (issue-limited), so drop 2 pk_add of combine tree.
// VALU/step: 55 -> 47.  DS/step: 1 -> 5.
//
// "memory" clobber on BOTH asm blocks: pins the queue ds_read (program
// order: before STEP_MAC) so the tail's lgkmcnt(0) is always ~36 insts
// (~195 cyc) after it — longer than the ~120 cyc ds_read latency — and
// stops next-iter loads from drifting between MAC and TAIL.
//
// Layout identical to R4-R10: 16 lanes/element, 4 elem/wave, 1024 waves =
// 1 wave/SIMD. Lane j holds h_j (hA) and h_{16+(j&3)} (hB, quad-repl).
// Rotation r delivers h_{(j-r)&15}; weights pre-permuted, pre-scaled by
// 2*log2(e) so tanh = 1 - 2*rcp(exp2(s)+1). Cross-step state rA,rB
// (post-rcp); h finished at the top of the next MAC (R9b pattern).
//
// x staging: R3-R10 wave-local LDS double buffer, zero barriers.

typedef float f32x2 __attribute__((ext_vector_type(2)));
typedef float f32x4 __attribute__((ext_vector_type(4)));

constexpr int Tn   = 2048;
constexpr int Hn   = 20;
constexpr int EPB  = 16;   // elements per 256-thread block
constexpr int SB   = 16;   // steps per staging block
constexpr int NBLK = Tn / SB;

__global__ __launch_bounds__(256, 1) void rnn_fwd(
    const float* __restrict__ x,     // [B, T, 4]
    const float* __restrict__ h0,    // [B, 20]
    const float* __restrict__ W_ih,  // [20, 4]
    const float* __restrict__ W_hh,  // [20, 20]
    const float* __restrict__ b_ih,  // [20]
    const float* __restrict__ b_hh,  // [20]
    const float* __restrict__ fc_w,  // [4, 20]
    const float* __restrict__ fc_b,  // [4]
    float* __restrict__ out)         // [B, 4]
{
    __shared__ __align__(16) f32x4 xlds[2][EPB][SB + 1];
    __shared__ float hsh[EPB][24];

    const int tid  = threadIdx.x;
    const int j    = tid & 15;            // lane within row = A-target unit
    const int e    = tid >> 4;            // element slot in block (0..15)
    const int b    = blockIdx.x * EPB + e;
    const int uB   = 16 + (j & 3);        // B-target unit
    const int lane = tid & 63;            // lane within wave

    // bpermute byte-indices for rotations r=12..15 (within 16-lane rows)
    const int i12 = (((lane & ~15) | ((lane - 12) & 15))) << 2;
    const int i13 = (((lane & ~15) | ((lane - 13) & 15))) << 2;
    const int i14 = (((lane & ~15) | ((lane - 14) & 15))) << 2;
    const int i15 = (((lane & ~15) | ((lane - 15) & 15))) << 2;

    const float S = 2.88539008177792681472f;  // 2/ln(2)

    // Rotation weights: lo = A-chain (unit j), hi = B-chain (unit uB).
    f32x2 w2[16];
#pragma unroll
    for (int r = 0; r < 16; ++r) {
        const int k = (j - r) & 15;       // unit delivered by rotation r
        w2[r] = f32x2{S * W_hh[j * Hn + k], S * W_hh[uB * Hn + k]};
    }
    // Quad-rotation weights: rotation c delivers h_{16+((j+c)&3)}.
    f32x2 wqr[4], xiw[4];
#pragma unroll
    for (int c = 0; c < 4; ++c) {
        const int qc = 16 + ((j + c) & 3);
        wqr[c] = f32x2{S * W_hh[j * Hn + qc], S * W_hh[uB * Hn + qc]};
        xiw[c] = f32x2{S * W_ih[j * 4 + c],  S * W_ih[uB * 4 + c]};
    }
    f32x2 bias2 = f32x2{S * (b_ih[j] + b_hh[j]), S * (b_ih[uB] + b_hh[uB])};

    // ---- initial state: seed r so that h = -2*r + 1 reproduces h0 ----
    float rA = 0.5f * (1.0f - h0[b * Hn + j]);
    float rB = 0.5f * (1.0f - h0[b * Hn + uB]);

    const f32x4* __restrict__ xp =
        reinterpret_cast<const f32x4*>(x) + (size_t)b * Tn;

#define DPPM " row_mask:0xf bank_mask:0xf\n\t"
#define PKB  " op_sel:[0,0,0] op_sel_hi:[1,0,1]\n\t"   /* bcast src1 word0 */
#define CLB  "v40","v41","v42","v43","v44","v45","v46","v47","v48","v49",     \
             "v50","v51","v52","v53","v54","v55","v56","v57","v58","v59",     \
             "v60","v61","v62","v63"

    // MAC: finish tanh into fixed pairs, 4 bperms (DS), 14 movs, 16 pk_fma.
#define STEP_MAC() do {                                                       \
    asm volatile(                                                             \
  "v_fma_f32 v44, %[rB], -2.0, 1.0\n\t"            /* hB -> v44 (pair) */     \
  "v_fma_f32 v40, %[rA], -2.0, 1.0\n\t"            /* hA -> v40 (pair) */     \
  "ds_bpermute_b32 v50, %[i12], v40\n\t"                                      \
  "ds_bpermute_b32 v52, %[i13], v40\n\t"                                      \
  "ds_bpermute_b32 v54, %[i14], v40\n\t"                                      \
  "ds_bpermute_b32 v56, %[i15], v40\n\t"                                      \
  "v_pk_fma_f32 %[P], %[w0], v[40:41], %[P]" PKB   /* r=0 own hA */           \
  "v_mov_b32_dpp v42, v44 quad_perm:[1,2,3,0]" DPPM                           \
  "v_pk_fma_f32 %[Q], %[c0], v[44:45], %[Q]" PKB   /* quad own hB */          \
  "v_mov_b32_dpp v46, v44 quad_perm:[2,3,0,1]" DPPM                           \
  "v_pk_fma_f32 %[P], %[c1], v[42:43], %[P]" PKB                              \
  "v_mov_b32_dpp v48, v44 quad_perm:[3,0,1,2]" DPPM                           \
  "v_pk_fma_f32 %[Q], %[c2], v[46:47], %[Q]" PKB                              \
  "v_mov_b32_dpp v42, v40 row_ror:1"  DPPM                                    \
  "v_pk_fma_f32 %[P], %[c3], v[48:49], %[P]" PKB                              \
  "v_mov_b32_dpp v46, v40 row_ror:2"  DPPM                                    \
  "v_pk_fma_f32 %[Q], %[w1], v[42:43], %[Q]" PKB                              \
  "v_mov_b32_dpp v48, v40 row_ror:3"  DPPM                                    \
  "v_pk_fma_f32 %[P], %[w2], v[46:47], %[P]" PKB                              \
  "v_mov_b32_dpp v42, v40 row_ror:4"  DPPM                                    \
  "v_pk_fma_f32 %[Q], %[w3], v[48:49], %[Q]" PKB                              \
  "v_mov_b32_dpp v46, v40 row_ror:5"  DPPM                                    \
  "v_pk_fma_f32 %[P], %[w4], v[42:43], %[P]" PKB                              \
  "v_mov_b32_dpp v48, v40 row_ror:6"  DPPM                                    \
  "v_pk_fma_f32 %[Q], %[w5], v[46:47], %[Q]" PKB                              \
  "v_mov_b32_dpp v42, v40 row_ror:7"  DPPM                                    \
  "v_pk_fma_f32 %[P], %[w6], v[48:49], %[P]" PKB                              \
  "v_mov_b32_dpp v46, v40 row_ror:8"  DPPM                                    \
  "v_pk_fma_f32 %[Q], %[w7], v[42:43], %[Q]" PKB                              \
  "v_mov_b32_dpp v48, v40 row_ror:9"  DPPM                                    \
  "v_pk_fma_f32 %[P], %[w8], v[46:47], %[P]" PKB                              \
  "v_mov_b32_dpp v42, v40 row_ror:10" DPPM                                    \
  "v_pk_fma_f32 %[Q], %[w9], v[48:49], %[Q]" PKB                              \
  "v_mov_b32_dpp v46, v40 row_ror:11" DPPM                                    \
  "v_pk_fma_f32 %[P], %[w10], v[42:43], %[P]" PKB                             \
  "v_pk_fma_f32 %[Q], %[w11], v[46:47], %[Q]"                                 \
  " op_sel:[0,0,0] op_sel_hi:[1,0,1]"                                         \
  : [P] "+v"(xiP), [Q] "+v"(xiQ)                                              \
  : [rA] "v"(rA), [rB] "v"(rB),                                               \
    [w0] "v"(w2[0]), [w1] "v"(w2[1]),  [w2] "v"(w2[2]),  [w3] "v"(w2[3]),     \
    [w4] "v"(w2[4]), [w5] "v"(w2[5]),  [w6] "v"(w2[6]),  [w7] "v"(w2[7]),     \
    [w8] "v"(w2[8]), [w9] "v"(w2[9]),  [w10] "v"(w2[10]),[w11] "v"(w2[11]),   \
    [c0] "v"(wqr[0]), [c1] "v"(wqr[1]), [c2] "v"(wqr[2]), [c3] "v"(wqr[3]),   \
    [i12] "v"(i12), [i13] "v"(i13), [i14] "v"(i14), [i15] "v"(i15)            \
  : CLB, "memory");                                                           \
} while (0)

    // Tail: wait bperms, 4 pk_fma, combine + exp/rcp, xi(t+1) in the gaps.
#define STEP_TAIL(XV) do {                                                    \
    f32x2 xa_ = __builtin_shufflevector((XV), (XV), 0, 1);                    \
    f32x2 xb_ = __builtin_shufflevector((XV), (XV), 2, 3);                    \
    asm volatile(                                                             \
  "s_waitcnt lgkmcnt(0)\n\t"                                                  \
  "v_pk_fma_f32 %[P], %[w12], v[50:51], %[P]" PKB   /* r=12 */                \
  "v_pk_fma_f32 %[Q], %[w13], v[52:53], %[Q]" PKB   /* r=13 */                \
  "v_pk_fma_f32 %[P], %[w14], v[54:55], %[P]" PKB   /* r=14 */                \
  "v_pk_fma_f32 %[Q], %[w15], v[56:57], %[Q]" PKB   /* r=15 */                \
  "v_pk_add_f32 v[58:59], %[P], %[Q]\n\t"                                     \
  "v_pk_fma_f32 %[P], %[x0], %[xa], %[b2]" PKB                                \
  "v_pk_mul_f32 %[Q], %[x1], %[xa] op_sel:[0,1] op_sel_hi:[1,1]\n\t"          \
  "v_exp_f32 v60, v59\n\t"                                                    \
  "v_pk_fma_f32 %[P], %[x2], %[xb], %[P]" PKB                                 \
  "v_exp_f32 v61, v58\n\t"                                                    \
  "v_pk_fma_f32 %[Q], %[x3], %[xb], %[Q] op_sel:[0,1,0] op_sel_hi:[1,1,1]\n\t"\
  "v_add_f32 v60, 1.0, v60\n\t"                                               \
  "v_add_f32 v61, 1.0, v61\n\t"                                               \
  "v_rcp_f32 %[rB], v60\n\t"                                                  \
  "v_rcp_f32 %[rA], v61"                                                      \
  : [rA] "=&v"(rA), [rB] "=&v"(rB),                                           \
    [P] "+v"(xiP), [Q] "+v"(xiQ)                                              \
  : [w12] "v"(w2[12]), [w13] "v"(w2[13]), [w14] "v"(w2[14]), [w15] "v"(w2[15]),\
    [xa] "v"(xa_), [xb] "v"(xb_),                                             \
    [x0] "v"(xiw[0]), [x1] "v"(xiw[1]), [x2] "v"(xiw[2]), [x3] "v"(xiw[3]),   \
    [b2] "v"(bias2)                                                           \
  : CLB, "memory");                                                           \
} while (0)

#define STEP(XV) do { STEP_MAC(); STEP_TAIL(XV); } while (0)

    // ---- prologue: stage block 0, compute xi(0), prime queue at x[1..3] ----
    xlds[0][e][j] = xp[j];                // lane j -> row j (coalesced)
    f32x4 x0v = xp[0];
    f32x2 xiP, xiQ;
    xiP[0] = __builtin_fmaf(x0v[2], xiw[2][0],
             __builtin_fmaf(x0v[0], xiw[0][0], bias2[0]));
    xiP[1] = __builtin_fmaf(x0v[2], xiw[2][1],
             __builtin_fmaf(x0v[0], xiw[0][1], bias2[1]));
    xiQ[0] = __builtin_fmaf(x0v[3], xiw[3][0], x0v[1] * xiw[1][0]);
    xiQ[1] = __builtin_fmaf(x0v[3], xiw[3][1], x0v[1] * xiw[1][1]);
    f32x4 q0 = xlds[0][e][1];
    f32x4 q1 = xlds[0][e][2];
    f32x4 q2 = xlds[0][e][3];

    int cur = 0;
#pragma unroll 1
    for (int k = 0; k < NBLK; ++k) {
        const int kn = (k + 1 < NBLK) ? (k + 1) : (NBLK - 1);  // tail reload
        f32x4 xr = xp[kn * SB + j];       // global load at block TOP
        const int nxt = cur ^ 1;
#pragma unroll
        for (int s = 0; s < SB - 4; ++s) {                     // s = 0..11
            f32x4 xv = q0; q0 = q1; q1 = q2;
            q2 = xlds[cur][e][s + 4];     // 3-step LDS lookahead (shifted)
            STEP(xv);
        }
        xlds[nxt][e][j] = xr;             // prior reads of nxt already issued
        { f32x4 xv = q0; q0 = q1; q1 = q2; q2 = xlds[nxt][e][0]; STEP(xv); }
        { f32x4 xv = q0; q0 = q1; q1 = q2; q2 = xlds[nxt][e][1]; STEP(xv); }
        { f32x4 xv = q0; q0 = q1; q1 = q2; q2 = xlds[nxt][e][2]; STEP(xv); }
        { f32x4 xv = q0; q0 = q1; q1 = q2; q2 = xlds[nxt][e][3]; STEP(xv); }
        cur = nxt;
    }
#undef STEP
#undef STEP_MAC
#undef STEP_TAIL
#undef PKB
#undef DPPM
#undef CLB

    // ---- finish the last tanh: h(2048) = -2*r(2047) + 1 ----
    const float hAf = __builtin_fmaf(-2.0f, rA, 1.0f);
    const float hBf = __builtin_fmaf(-2.0f, rB, 1.0f);

    // ---- epilogue: out[b][m] = fc_b[m] + sum_k h[k] * fc_w[m][k] ----
    hsh[e][j] = hAf;                      // units 0..15
    if (j < 4) hsh[e][16 + j] = hBf;      // lane j holds unit 16+j
    if (j < 4) {
        float o = fc_b[j];
#pragma unroll
        for (int kk = 0; kk < Hn; ++kk)
            o = __builtin_fmaf(hsh[e][kk], fc_w[j * Hn + kk], o);
        out[b * 4 + j] = o;
    }
}

extern "C" void kernel_launch(void* const* d_in, const int* in_sizes, int n_in,
                              void* d_out, int out_size, void* d_ws, size_t ws_size,
                              hipStream_t stream) {
    const float* x    = (const float*)d_in[0];
    const float* h0   = (const float*)d_in[1];
    const float* W_ih = (const float*)d_in[2];
    const float* W_hh = (const float*)d_in[3];
    const float* b_ih = (const float*)d_in[4];
    const float* b_hh = (const float*)d_in[5];
    const float* fc_w = (const float*)d_in[6];
    const float* fc_b = (const float*)d_in[7];
    float* out = (float*)d_out;

    // 4096 elements / 16 per block = 256 blocks = 1024 waves = 1 wave/SIMD.
    rnn_fwd<<<dim3(256), dim3(256), 0, stream>>>(x, h0, W_ih, W_hh, b_ih, b_hh,
                                                 fc_w, fc_b, out);
}

// Round 7
// 380.779 us; speedup vs baseline: 1.1779x; 1.1161x over previous
//
#include <hip/hip_runtime.h>
#include <cstddef>

// Vanilla tanh-RNN: B=4096, T=2048, I=4, H=20, then Linear(20->4) on h_last.
//
// Round-12: all-VALU 49-inst step — bperms reverted, tanh affine folded
// into weights.
//
// Model (R6-R11, 6 kernels): VALU busy = 4.7 cyc/inst EXACTLY (R9b 258/55,
// R10 216/46, R11 214/47); wall = 4.7*N + ~85 cyc fixed (R6/R7/R9b gap
// 84-86 constant). DS-waits in the loop add 70-150 cyc of unhideable stall
// (R10: +104, R11: +69) -> DS offload refuted. Only lever: N_valu down.
//
// Changes vs R9b/R11:
//  * tanh affine FOLDED INTO WEIGHTS: h = 1-2r => W.h = rowsum(W) - 2(W.r).
//    Broadcast r (the rcp outputs) directly; rotation/quad weights scaled
//    by -2S; S*rowsum(W) added to bias. The per-step "h = -2r+1" fma pair
//    is GONE (h materialized once, in the epilogue). Exact transform.
//  * rcp writes rB->v44, rA->v40 (fixed even pairs, R11-validated): own-
//    unit and quad-own terms read v[40:41]/v[44:45] via word0-bcast, 0 movs.
//  * quad terms via 3 quad_perm rotations (R11-validated weights wqr).
//  * 2 chains (P,Q); r=1..15 via row_ror DPP movs (NO bperm, NO lgkmcnt,
//    no memory clobber — R9b discipline).
// VALU/step: 49 (MAC 18 mov + 20 pk_fma; TAIL 1 pk_add + 4 xi + 2 exp +
// 2 add + 2 rcp). DS/step: 1 (queue ds_read, compiler-managed).
//
// Fixed-reg state (v40/v44) crosses asm blocks; v40-v53 clobbered in both
// blocks so the allocator keeps every cross-asm value out of them
// (pattern validated R10/R11). Prologue seeds v40/v44; epilogue extracts.
//
// DPP hazards: first DPP read of v44 (quad) is 3 insts after its rcp
// write; first DPP read of v40 (ror:1) is 8 insts after. >=2 required.
//
// Layout identical to R4-R11: 16 lanes/element, 4 elem/wave, 1024 waves =
// 1 wave/SIMD. Lane j owns unit j (A) and unit 16+(j&3) (B, quad-repl).
// Rotation r delivers state of unit (j-r)&15; weights pre-permuted.
// exp2-domain scaling S = 2/ln2 baked into all weights.
//
// x staging: R3-R11 wave-local LDS double buffer, zero barriers.

typedef float f32x2 __attribute__((ext_vector_type(2)));
typedef float f32x4 __attribute__((ext_vector_type(4)));

constexpr int Tn   = 2048;
constexpr int Hn   = 20;
constexpr int EPB  = 16;   // elements per 256-thread block
constexpr int SB   = 16;   // steps per staging block
constexpr int NBLK = Tn / SB;

__global__ __launch_bounds__(256, 1) void rnn_fwd(
    const float* __restrict__ x,     // [B, T, 4]
    const float* __restrict__ h0,    // [B, 20]
    const float* __restrict__ W_ih,  // [20, 4]
    const float* __restrict__ W_hh,  // [20, 20]
    const float* __restrict__ b_ih,  // [20]
    const float* __restrict__ b_hh,  // [20]
    const float* __restrict__ fc_w,  // [4, 20]
    const float* __restrict__ fc_b,  // [4]
    float* __restrict__ out)         // [B, 4]
{
    __shared__ __align__(16) f32x4 xlds[2][EPB][SB + 1];
    __shared__ float hsh[EPB][24];

    const int tid = threadIdx.x;
    const int j   = tid & 15;             // lane within row = A-target unit
    const int e   = tid >> 4;             // element slot in block (0..15)
    const int b   = blockIdx.x * EPB + e;
    const int uB  = 16 + (j & 3);         // B-target unit

    const float S = 2.88539008177792681472f;  // 2/ln(2)
    const float M = -2.0f * S;                // MAC-on-r scale

    // Rotation weights on r: lo = A-chain (unit j), hi = B-chain (unit uB).
    f32x2 w2[16];
#pragma unroll
    for (int r = 0; r < 16; ++r) {
        const int k = (j - r) & 15;       // unit delivered by rotation r
        w2[r] = f32x2{M * W_hh[j * Hn + k], M * W_hh[uB * Hn + k]};
    }
    // Quad-rotation weights: rotation c delivers unit 16+((j+c)&3).
    f32x2 wqr[4], xiw[4];
#pragma unroll
    for (int c = 0; c < 4; ++c) {
        const int qc = 16 + ((j + c) & 3);
        wqr[c] = f32x2{M * W_hh[j * Hn + qc], M * W_hh[uB * Hn + qc]};
        xiw[c] = f32x2{S * W_ih[j * 4 + c],  S * W_ih[uB * 4 + c]};
    }
    // Bias absorbs S*rowsum(W_hh) from the h = 1-2r expansion.
    float rsA = 0.0f, rsB = 0.0f;
#pragma unroll
    for (int k = 0; k < Hn; ++k) {
        rsA += W_hh[j  * Hn + k];
        rsB += W_hh[uB * Hn + k];
    }
    f32x2 bias2 = f32x2{S * (b_ih[j]  + b_hh[j]  + rsA),
                        S * (b_ih[uB] + b_hh[uB] + rsB)};

    // ---- initial state: r = (1 - h0)/2 so that h = 1 - 2r ----
    const float r0A = 0.5f * (1.0f - h0[b * Hn + j]);
    const float r0B = 0.5f * (1.0f - h0[b * Hn + uB]);

    const f32x4* __restrict__ xp =
        reinterpret_cast<const f32x4*>(x) + (size_t)b * Tn;

#define DPPM " row_mask:0xf bank_mask:0xf\n\t"
#define PKB  " op_sel:[0,0,0] op_sel_hi:[1,0,1]\n\t"   /* bcast src1 word0 */
#define CLB  "v40","v41","v42","v43","v44","v45","v46","v47","v48","v49",     \
             "v50","v51","v52","v53"

    // MAC: 18 DPP movs + 20 pk_fma on r-state in v40 (rA) / v44 (rB).
#define STEP_MAC() do {                                                       \
    asm volatile(                                                             \
  "v_pk_fma_f32 %[Q], %[c0], v[44:45], %[Q]" PKB   /* quad own rB */          \
  "v_mov_b32_dpp v42, v44 quad_perm:[1,2,3,0]" DPPM                           \
  "v_pk_fma_f32 %[P], %[w0], v[40:41], %[P]" PKB   /* r=0 own rA */           \
  "v_mov_b32_dpp v46, v44 quad_perm:[2,3,0,1]" DPPM                           \
  "v_pk_fma_f32 %[Q], %[c1], v[42:43], %[Q]" PKB                              \
  "v_mov_b32_dpp v48, v44 quad_perm:[3,0,1,2]" DPPM                           \
  "v_pk_fma_f32 %[P], %[c2], v[46:47], %[P]" PKB                              \
  "v_mov_b32_dpp v42, v40 row_ror:1"  DPPM                                    \
  "v_pk_fma_f32 %[Q], %[c3], v[48:49], %[Q]" PKB                              \
  "v_mov_b32_dpp v46, v40 row_ror:2"  DPPM                                    \
  "v_pk_fma_f32 %[P], %[w1], v[42:43], %[P]" PKB                              \
  "v_mov_b32_dpp v48, v40 row_ror:3"  DPPM                                    \
  "v_pk_fma_f32 %[Q], %[w2], v[46:47], %[Q]" PKB                              \
  "v_mov_b32_dpp v42, v40 row_ror:4"  DPPM                                    \
  "v_pk_fma_f32 %[P], %[w3], v[48:49], %[P]" PKB                              \
  "v_mov_b32_dpp v46, v40 row_ror:5"  DPPM                                    \
  "v_pk_fma_f32 %[Q], %[w4], v[42:43], %[Q]" PKB                              \
  "v_mov_b32_dpp v48, v40 row_ror:6"  DPPM                                    \
  "v_pk_fma_f32 %[P], %[w5], v[46:47], %[P]" PKB                              \
  "v_mov_b32_dpp v42, v40 row_ror:7"  DPPM                                    \
  "v_pk_fma_f32 %[Q], %[w6], v[48:49], %[Q]" PKB                              \
  "v_mov_b32_dpp v46, v40 row_ror:8"  DPPM                                    \
  "v_pk_fma_f32 %[P], %[w7], v[42:43], %[P]" PKB                              \
  "v_mov_b32_dpp v48, v40 row_ror:9"  DPPM                                    \
  "v_pk_fma_f32 %[Q], %[w8], v[46:47], %[Q]" PKB                              \
  "v_mov_b32_dpp v42, v40 row_ror:10" DPPM                                    \
  "v_pk_fma_f32 %[P], %[w9], v[48:49], %[P]" PKB                              \
  "v_mov_b32_dpp v46, v40 row_ror:11" DPPM                                    \
  "v_pk_fma_f32 %[Q], %[w10], v[42:43], %[Q]" PKB                             \
  "v_mov_b32_dpp v48, v40 row_ror:12" DPPM                                    \
  "v_pk_fma_f32 %[P], %[w11], v[46:47], %[P]" PKB                             \
  "v_mov_b32_dpp v42, v40 row_ror:13" DPPM                                    \
  "v_pk_fma_f32 %[Q], %[w12], v[48:49], %[Q]" PKB                             \
  "v_mov_b32_dpp v46, v40 row_ror:14" DPPM                                    \
  "v_pk_fma_f32 %[P], %[w13], v[42:43], %[P]" PKB                             \
  "v_mov_b32_dpp v48, v40 row_ror:15" DPPM                                    \
  "v_pk_fma_f32 %[Q], %[w14], v[46:47], %[Q]" PKB                             \
  "v_pk_fma_f32 %[P], %[w15], v[48:49], %[P]"                                 \
  " op_sel:[0,0,0] op_sel_hi:[1,0,1]"                                         \
  : [P] "+v"(xiP), [Q] "+v"(xiQ)                                              \
  : [w0] "v"(w2[0]), [w1] "v"(w2[1]),  [w2] "v"(w2[2]),  [w3] "v"(w2[3]),     \
    [w4] "v"(w2[4]), [w5] "v"(w2[5]),  [w6] "v"(w2[6]),  [w7] "v"(w2[7]),     \
    [w8] "v"(w2[8]), [w9] "v"(w2[9]),  [w10] "v"(w2[10]),[w11] "v"(w2[11]),   \
    [w12] "v"(w2[12]),[w13] "v"(w2[13]),[w14] "v"(w2[14]),[w15] "v"(w2[15]),  \
    [c0] "v"(wqr[0]), [c1] "v"(wqr[1]), [c2] "v"(wqr[2]), [c3] "v"(wqr[3])    \
  : CLB);                                                                     \
} while (0)

    // Tail: combine + exp/rcp -> v44 (rB), v40 (rA); xi(t+1) in the gaps.
#define STEP_TAIL(XV) do {                                                    \
    f32x2 xa_ = __builtin_shufflevector((XV), (XV), 0, 1);                    \
    f32x2 xb_ = __builtin_shufflevector((XV), (XV), 2, 3);                    \
    asm volatile(                                                             \
  "v_pk_add_f32 v[50:51], %[P], %[Q]\n\t"                                     \
  "v_pk_fma_f32 %[P], %[x0], %[xa], %[b2]" PKB                                \
  "v_pk_mul_f32 %[Q], %[x1], %[xa] op_sel:[0,1] op_sel_hi:[1,1]\n\t"          \
  "v_exp_f32 v52, v51\n\t"                                                    \
  "v_pk_fma_f32 %[P], %[x2], %[xb], %[P]" PKB                                 \
  "v_exp_f32 v53, v50\n\t"                                                    \
  "v_pk_fma_f32 %[Q], %[x3], %[xb], %[Q] op_sel:[0,1,0] op_sel_hi:[1,1,1]\n\t"\
  "v_add_f32 v52, 1.0, v52\n\t"                                               \
  "v_add_f32 v53, 1.0, v53\n\t"                                               \
  "v_rcp_f32 v44, v52\n\t"                                                    \
  "v_rcp_f32 v40, v53"                                                        \
  : [P] "+v"(xiP), [Q] "+v"(xiQ)                                              \
  : [xa] "v"(xa_), [xb] "v"(xb_),                                             \
    [x0] "v"(xiw[0]), [x1] "v"(xiw[1]), [x2] "v"(xiw[2]), [x3] "v"(xiw[3]),   \
    [b2] "v"(bias2)                                                           \
  : CLB);                                                                     \
} while (0)

#define STEP(XV) do { STEP_MAC(); STEP_TAIL(XV); } while (0)

    // ---- prologue: stage block 0, compute xi(0), seed v40/v44 ----
    xlds[0][e][j] = xp[j];                // lane j -> row j (coalesced)
    f32x4 x0v = xp[0];
    f32x2 xiP, xiQ;
    xiP[0] = __builtin_fmaf(x0v[2], xiw[2][0],
             __builtin_fmaf(x0v[0], xiw[0][0], bias2[0]));
    xiP[1] = __builtin_fmaf(x0v[2], xiw[2][1],
             __builtin_fmaf(x0v[0], xiw[0][1], bias2[1]));
    xiQ[0] = __builtin_fmaf(x0v[3], xiw[3][0], x0v[1] * xiw[1][0]);
    xiQ[1] = __builtin_fmaf(x0v[3], xiw[3][1], x0v[1] * xiw[1][1]);
    asm volatile("v_mov_b32 v40, %0\n\tv_mov_b32 v44, %1"
                 :: "v"(r0A), "v"(r0B) : "v40", "v44");
    f32x4 q0 = xlds[0][e][1];
    f32x4 q1 = xlds[0][e][2];
    f32x4 q2 = xlds[0][e][3];

    int cur = 0;
#pragma unroll 1
    for (int k = 0; k < NBLK; ++k) {
        const int kn = (k + 1 < NBLK) ? (k + 1) : (NBLK - 1);  // tail reload
        f32x4 xr = xp[kn * SB + j];       // global load at block TOP
        const int nxt = cur ^ 1;
#pragma unroll
        for (int s = 0; s < SB - 4; ++s) {                     // s = 0..11
            f32x4 xv = q0; q0 = q1; q1 = q2;
            q2 = xlds[cur][e][s + 4];     // 3-step LDS lookahead (shifted)
            STEP(xv);
        }
        xlds[nxt][e][j] = xr;             // prior reads of nxt already issued
        { f32x4 xv = q0; q0 = q1; q1 = q2; q2 = xlds[nxt][e][0]; STEP(xv); }
        { f32x4 xv = q0; q0 = q1; q1 = q2; q2 = xlds[nxt][e][1]; STEP(xv); }
        { f32x4 xv = q0; q0 = q1; q1 = q2; q2 = xlds[nxt][e][2]; STEP(xv); }
        { f32x4 xv = q0; q0 = q1; q1 = q2; q2 = xlds[nxt][e][3]; STEP(xv); }
        cur = nxt;
    }
#undef STEP
#undef STEP_MAC
#undef STEP_TAIL
#undef PKB
#undef DPPM
#undef CLB

    // ---- extract final state and finish the last tanh ----
    float rAf, rBf;
    asm volatile("v_mov_b32 %0, v40\n\tv_mov_b32 %1, v44"
                 : "=v"(rAf), "=v"(rBf));
    const float hAf = __builtin_fmaf(-2.0f, rAf, 1.0f);
    const float hBf = __builtin_fmaf(-2.0f, rBf, 1.0f);

    // ---- epilogue: out[b][m] = fc_b[m] + sum_k h[k] * fc_w[m][k] ----
    hsh[e][j] = hAf;                      // units 0..15
    if (j < 4) hsh[e][16 + j] = hBf;      // lane j holds unit 16+j
    if (j < 4) {
        float o = fc_b[j];
#pragma unroll
        for (int kk = 0; kk < Hn; ++kk)
            o = __builtin_fmaf(hsh[e][kk], fc_w[j * Hn + kk], o);
        out[b * 4 + j] = o;
    }
}

extern "C" void kernel_launch(void* const* d_in, const int* in_sizes, int n_in,
                              void* d_out, int out_size, void* d_ws, size_t ws_size,
                              hipStream_t stream) {
    const float* x    = (const float*)d_in[0];
    const float* h0   = (const float*)d_in[1];
    const float* W_ih = (const float*)d_in[2];
    const float* W_hh = (const float*)d_in[3];
    const float* b_ih = (const float*)d_in[4];
    const float* b_hh = (const float*)d_in[5];
    const float* fc_w = (const float*)d_in[6];
    const float* fc_b = (const float*)d_in[7];
    float* out = (float*)d_out;

    // 4096 elements / 16 per block = 256 blocks = 1024 waves = 1 wave/SIMD.
    rnn_fwd<<<dim3(256), dim3(256), 0, stream>>>(x, h0, W_ih, W_hh, b_ih, b_hh,
                                                 fc_w, fc_b, out);
}

// Round 8
// 365.624 us; speedup vs baseline: 1.2267x; 1.0414x over previous
//
#include <hip/hip_runtime.h>
#include <cstddef>

// Vanilla tanh-RNN: B=4096, T=2048, I=4, H=20, then Linear(20->4) on h_last.
//
// Round-13: register-only x pipeline (no LDS in the step loop) + pk'd +1.0.
//
// Confirmed law (R6-R12, 7 kernels, 4 exact fits): per SIMD,
//     wall = 4.7 cyc x N_valu + C,   C ~ 85 cyc/step.
// R12 (N=49): predicted 257-268 us, measured 267 us. VALU busy/inst = 4.73.
//
// This round:
//  * N: 49 -> 48 — the two scalar v_add 1.0 merge into one v_pk_add
//    against a {1,1} register pair (bit-identical arithmetic).
//  * C-probe: the only non-VALU machinery left in the loop is the LDS
//    x-queue (ds_write + ds_read_b128 + lgkm waits). Replace with a pure
//    register pipeline: bufA/bufB = 8 x f32x4 each (64 VGPRs), refilled by
//    global_load_dwordx4 straight from HBM/L2 (16 lanes of an element read
//    the SAME address — HW broadcast). Refill sits 8 steps (~2400 cyc)
//    ahead of consumption (HBM latency ~900). Statically indexed, fully
//    unrolled (no runtime buffer index -> no scratch). Zero LDS ops, zero
//    lgkmcnt in the step loop.
//
// Everything else identical to R12 (validated):
//  * tanh affine folded into weights: h = 1-2r; weights -2S, bias +S*rowsum.
//  * state lives in fixed even pairs v40 (rA) / v44 (rB); own-unit and
//    quad-own pk_fmas read v[40:41]/v[44:45] via op_sel word0-bcast.
//  * 3 quad_perm rotations + 15 row_ror rotations, 2 chains (P,Q).
//  * rcp writes v44/v40 directly; epilogue extracts and finishes tanh.
//
// N = 48: MAC 18 mov + 20 pk_fma = 38; tail 1 pk_add + 4 xi + 2 exp +
// 1 pk_add(+1) + 2 rcp = 10.
//
// Prediction: if C was LDS-related -> ~230 us dispatch, VALUBusy ~83%,
// LDS_BANK_CONFLICT ~0. If C unchanged -> ~264 us (then C is issue/trans
// overhead and this design is within ~5% of its ceiling).

typedef float f32x2 __attribute__((ext_vector_type(2)));
typedef float f32x4 __attribute__((ext_vector_type(4)));

constexpr int Tn   = 2048;
constexpr int Hn   = 20;
constexpr int EPB  = 16;   // elements per 256-thread block
constexpr int SPI  = 16;   // steps per outer iteration (bufA 8 + bufB 8)
constexpr int NIT  = Tn / SPI;   // 128

__global__ __launch_bounds__(256, 1) void rnn_fwd(
    const float* __restrict__ x,     // [B, T, 4]
    const float* __restrict__ h0,    // [B, 20]
    const float* __restrict__ W_ih,  // [20, 4]
    const float* __restrict__ W_hh,  // [20, 20]
    const float* __restrict__ b_ih,  // [20]
    const float* __restrict__ b_hh,  // [20]
    const float* __restrict__ fc_w,  // [4, 20]
    const float* __restrict__ fc_b,  // [4]
    float* __restrict__ out)         // [B, 4]
{
    __shared__ float hsh[EPB][24];

    const int tid = threadIdx.x;
    const int j   = tid & 15;             // lane within row = A-target unit
    const int e   = tid >> 4;             // element slot in block (0..15)
    const int b   = blockIdx.x * EPB + e;
    const int uB  = 16 + (j & 3);         // B-target unit

    const float S = 2.88539008177792681472f;  // 2/ln(2)
    const float M = -2.0f * S;                // MAC-on-r scale

    // Rotation weights on r: lo = A-chain (unit j), hi = B-chain (unit uB).
    f32x2 w2[16];
#pragma unroll
    for (int r = 0; r < 16; ++r) {
        const int k = (j - r) & 15;       // unit delivered by rotation r
        w2[r] = f32x2{M * W_hh[j * Hn + k], M * W_hh[uB * Hn + k]};
    }
    // Quad-rotation weights: rotation c delivers unit 16+((j+c)&3).
    f32x2 wqr[4], xiw[4];
#pragma unroll
    for (int c = 0; c < 4; ++c) {
        const int qc = 16 + ((j + c) & 3);
        wqr[c] = f32x2{M * W_hh[j * Hn + qc], M * W_hh[uB * Hn + qc]};
        xiw[c] = f32x2{S * W_ih[j * 4 + c],  S * W_ih[uB * 4 + c]};
    }
    // Bias absorbs S*rowsum(W_hh) from the h = 1-2r expansion.
    float rsA = 0.0f, rsB = 0.0f;
#pragma unroll
    for (int k = 0; k < Hn; ++k) {
        rsA += W_hh[j  * Hn + k];
        rsB += W_hh[uB * Hn + k];
    }
    f32x2 bias2 = f32x2{S * (b_ih[j]  + b_hh[j]  + rsA),
                        S * (b_ih[uB] + b_hh[uB] + rsB)};
    const f32x2 one2 = f32x2{1.0f, 1.0f};

    // ---- initial state: r = (1 - h0)/2 so that h = 1 - 2r ----
    const float r0A = 0.5f * (1.0f - h0[b * Hn + j]);
    const float r0B = 0.5f * (1.0f - h0[b * Hn + uB]);

    const f32x4* __restrict__ xp =
        reinterpret_cast<const f32x4*>(x) + (size_t)b * Tn;

#define DPPM " row_mask:0xf bank_mask:0xf\n\t"
#define PKB  " op_sel:[0,0,0] op_sel_hi:[1,0,1]\n\t"   /* bcast src1 word0 */
#define CLB  "v40","v41","v42","v43","v44","v45","v46","v47","v48","v49",     \
             "v50","v51","v52","v53"

    // MAC: 18 DPP movs + 20 pk_fma on r-state in v40 (rA) / v44 (rB).
#define STEP_MAC() do {                                                       \
    asm volatile(                                                             \
  "v_pk_fma_f32 %[Q], %[c0], v[44:45], %[Q]" PKB   /* quad own rB */          \
  "v_mov_b32_dpp v42, v44 quad_perm:[1,2,3,0]" DPPM                           \
  "v_pk_fma_f32 %[P], %[w0], v[40:41], %[P]" PKB   /* r=0 own rA */           \
  "v_mov_b32_dpp v46, v44 quad_perm:[2,3,0,1]" DPPM                           \
  "v_pk_fma_f32 %[Q], %[c1], v[42:43], %[Q]" PKB                              \
  "v_mov_b32_dpp v48, v44 quad_perm:[3,0,1,2]" DPPM                           \
  "v_pk_fma_f32 %[P], %[c2], v[46:47], %[P]" PKB                              \
  "v_mov_b32_dpp v42, v40 row_ror:1"  DPPM                                    \
  "v_pk_fma_f32 %[Q], %[c3], v[48:49], %[Q]" PKB                              \
  "v_mov_b32_dpp v46, v40 row_ror:2"  DPPM                                    \
  "v_pk_fma_f32 %[P], %[w1], v[42:43], %[P]" PKB                              \
  "v_mov_b32_dpp v48, v40 row_ror:3"  DPPM                                    \
  "v_pk_fma_f32 %[Q], %[w2], v[46:47], %[Q]" PKB                              \
  "v_mov_b32_dpp v42, v40 row_ror:4"  DPPM                                    \
  "v_pk_fma_f32 %[P], %[w3], v[48:49], %[P]" PKB                              \
  "v_mov_b32_dpp v46, v40 row_ror:5"  DPPM                                    \
  "v_pk_fma_f32 %[Q], %[w4], v[42:43], %[Q]" PKB                              \
  "v_mov_b32_dpp v48, v40 row_ror:6"  DPPM                                    \
  "v_pk_fma_f32 %[P], %[w5], v[46:47], %[P]" PKB                              \
  "v_mov_b32_dpp v42, v40 row_ror:7"  DPPM                                    \
  "v_pk_fma_f32 %[Q], %[w6], v[48:49], %[Q]" PKB                              \
  "v_mov_b32_dpp v46, v40 row_ror:8"  DPPM                                    \
  "v_pk_fma_f32 %[P], %[w7], v[42:43], %[P]" PKB                              \
  "v_mov_b32_dpp v48, v40 row_ror:9"  DPPM                                    \
  "v_pk_fma_f32 %[Q], %[w8], v[46:47], %[Q]" PKB                              \
  "v_mov_b32_dpp v42, v40 row_ror:10" DPPM                                    \
  "v_pk_fma_f32 %[P], %[w9], v[48:49], %[P]" PKB                              \
  "v_mov_b32_dpp v46, v40 row_ror:11" DPPM                                    \
  "v_pk_fma_f32 %[Q], %[w10], v[42:43], %[Q]" PKB                             \
  "v_mov_b32_dpp v48, v40 row_ror:12" DPPM                                    \
  "v_pk_fma_f32 %[P], %[w11], v[46:47], %[P]" PKB                             \
  "v_mov_b32_dpp v42, v40 row_ror:13" DPPM                                    \
  "v_pk_fma_f32 %[Q], %[w12], v[48:49], %[Q]" PKB                             \
  "v_mov_b32_dpp v46, v40 row_ror:14" DPPM                                    \
  "v_pk_fma_f32 %[P], %[w13], v[42:43], %[P]" PKB                             \
  "v_mov_b32_dpp v48, v40 row_ror:15" DPPM                                    \
  "v_pk_fma_f32 %[Q], %[w14], v[46:47], %[Q]" PKB                             \
  "v_pk_fma_f32 %[P], %[w15], v[48:49], %[P]"                                 \
  " op_sel:[0,0,0] op_sel_hi:[1,0,1]"                                         \
  : [P] "+v"(xiP), [Q] "+v"(xiQ)                                              \
  : [w0] "v"(w2[0]), [w1] "v"(w2[1]),  [w2] "v"(w2[2]),  [w3] "v"(w2[3]),     \
    [w4] "v"(w2[4]), [w5] "v"(w2[5]),  [w6] "v"(w2[6]),  [w7] "v"(w2[7]),     \
    [w8] "v"(w2[8]), [w9] "v"(w2[9]),  [w10] "v"(w2[10]),[w11] "v"(w2[11]),   \
    [w12] "v"(w2[12]),[w13] "v"(w2[13]),[w14] "v"(w2[14]),[w15] "v"(w2[15]),  \
    [c0] "v"(wqr[0]), [c1] "v"(wqr[1]), [c2] "v"(wqr[2]), [c3] "v"(wqr[3])    \
  : CLB);                                                                     \
} while (0)

    // Tail: combine + exp / pk'd +1 / rcp -> v44 (rB), v40 (rA);
    // xi(t+1) interleaved in the gaps.
#define STEP_TAIL(XV) do {                                                    \
    f32x2 xa_ = __builtin_shufflevector((XV), (XV), 0, 1);                    \
    f32x2 xb_ = __builtin_shufflevector((XV), (XV), 2, 3);                    \
    asm volatile(                                                             \
  "v_pk_add_f32 v[50:51], %[P], %[Q]\n\t"                                     \
  "v_pk_fma_f32 %[P], %[x0], %[xa], %[b2]" PKB                                \
  "v_pk_mul_f32 %[Q], %[x1], %[xa] op_sel:[0,1] op_sel_hi:[1,1]\n\t"          \
  "v_exp_f32 v52, v51\n\t"                                                    \
  "v_pk_fma_f32 %[P], %[x2], %[xb], %[P]" PKB                                 \
  "v_exp_f32 v53, v50\n\t"                                                    \
  "v_pk_fma_f32 %[Q], %[x3], %[xb], %[Q] op_sel:[0,1,0] op_sel_hi:[1,1,1]\n\t"\
  "v_pk_add_f32 v[52:53], v[52:53], %[one]\n\t"                               \
  "v_rcp_f32 v44, v52\n\t"                                                    \
  "v_rcp_f32 v40, v53"                                                        \
  : [P] "+v"(xiP), [Q] "+v"(xiQ)                                              \
  : [xa] "v"(xa_), [xb] "v"(xb_),                                             \
    [x0] "v"(xiw[0]), [x1] "v"(xiw[1]), [x2] "v"(xiw[2]), [x3] "v"(xiw[3]),   \
    [b2] "v"(bias2), [one] "v"(one2)                                          \
  : CLB);                                                                     \
} while (0)

#define STEP(XV) do { STEP_MAC(); STEP_TAIL(XV); } while (0)

    // ---- prologue: register x-queues, xi(0), seed v40/v44 ----
    f32x4 bufA[8], bufB[8];
#pragma unroll
    for (int s = 0; s < 8; ++s) bufA[s] = xp[s];
#pragma unroll
    for (int s = 0; s < 8; ++s) bufB[s] = xp[8 + s];

    f32x4 x0v = bufA[0];
    f32x2 xiP, xiQ;
    xiP[0] = __builtin_fmaf(x0v[2], xiw[2][0],
             __builtin_fmaf(x0v[0], xiw[0][0], bias2[0]));
    xiP[1] = __builtin_fmaf(x0v[2], xiw[2][1],
             __builtin_fmaf(x0v[0], xiw[0][1], bias2[1]));
    xiQ[0] = __builtin_fmaf(x0v[3], xiw[3][0], x0v[1] * xiw[1][0]);
    xiQ[1] = __builtin_fmaf(x0v[3], xiw[3][1], x0v[1] * xiw[1][1]);
    asm volatile("v_mov_b32 v40, %0\n\tv_mov_b32 v44, %1"
                 :: "v"(r0A), "v"(r0B) : "v40", "v44");

    // NOTE on step/xi phasing (unchanged from R8-R12): STEP(xv) consumes the
    // PREVIOUS tail's xi accumulators and queues xi for xv's SUCCESSOR; the
    // xv passed at global step t is x[t+1].
#pragma unroll 1
    for (int k = 0; k < NIT; ++k) {
        const int kn = (k + 1 < NIT) ? (k + 1) : (NIT - 1);    // tail guard
        // consume bufA = x[16k .. 16k+7] (as xv for steps 16k-1 .. 16k+6)
        { STEP(bufA[1]); }  { STEP(bufA[2]); }
        { STEP(bufA[3]); }  { STEP(bufA[4]); }
        { STEP(bufA[5]); }  { STEP(bufA[6]); }
        { STEP(bufA[7]); }  { STEP(bufB[0]); }
        // refill bufA <- x[16(k+1) .. +7]   (consumed 8 steps from now)
#pragma unroll
        for (int s = 0; s < 8; ++s) bufA[s] = xp[kn * SPI + s];
        // consume bufB = x[16k+8 .. 16k+15]
        { STEP(bufB[1]); }  { STEP(bufB[2]); }
        { STEP(bufB[3]); }  { STEP(bufB[4]); }
        { STEP(bufB[5]); }  { STEP(bufB[6]); }
        { STEP(bufB[7]); }  { STEP(bufA[0]); }   // bufA already refilled
        // refill bufB <- x[16(k+1)+8 .. +15]
#pragma unroll
        for (int s = 0; s < 8; ++s) bufB[s] = xp[kn * SPI + 8 + s];
    }
#undef STEP
#undef STEP_MAC
#undef STEP_TAIL
#undef PKB
#undef DPPM
#undef CLB

    // ---- extract final state and finish the last tanh ----
    float rAf, rBf;
    asm volatile("v_mov_b32 %0, v40\n\tv_mov_b32 %1, v44"
                 : "=v"(rAf), "=v"(rBf));
    const float hAf = __builtin_fmaf(-2.0f, rAf, 1.0f);
    const float hBf = __builtin_fmaf(-2.0f, rBf, 1.0f);

    // ---- epilogue: out[b][m] = fc_b[m] + sum_k h[k] * fc_w[m][k] ----
    hsh[e][j] = hAf;                      // units 0..15
    if (j < 4) hsh[e][16 + j] = hBf;      // lane j holds unit 16+j
    __builtin_amdgcn_s_waitcnt(0);        // LDS visibility within wave
    if (j < 4) {
        float o = fc_b[j];
#pragma unroll
        for (int kk = 0; kk < Hn; ++kk)
            o = __builtin_fmaf(hsh[e][kk], fc_w[j * Hn + kk], o);
        out[b * 4 + j] = o;
    }
}

extern "C" void kernel_launch(void* const* d_in, const int* in_sizes, int n_in,
                              void* d_out, int out_size, void* d_ws, size_t ws_size,
                              hipStream_t stream) {
    const float* x    = (const float*)d_in[0];
    const float* h0   = (const float*)d_in[1];
    const float* W_ih = (const float*)d_in[2];
    const float* W_hh = (const float*)d_in[3];
    const float* b_ih = (const float*)d_in[4];
    const float* b_hh = (const float*)d_in[5];
    const float* fc_w = (const float*)d_in[6];
    const float* fc_b = (const float*)d_in[7];
    float* out = (float*)d_out;

    // 4096 elements / 16 per block = 256 blocks = 1024 waves = 1 wave/SIMD.
    rnn_fwd<<<dim3(256), dim3(256), 0, stream>>>(x, h0, W_ih, W_hh, b_ih, b_hh,
                                                 fc_w, fc_b, out);
}